// Round 2
// baseline (20.690 us; speedup 1.0000x reference)
//
#include <hip/hip_runtime.h>
#include <math.h>

// Problem constants (match reference file).
#define CC 2048   // clusters
#define PP 128    // max points per cluster
#define EE 2048   // edges

__global__ __launch_bounds__(256) void clust_geo_edge_kernel(
    const float* __restrict__ data,        // (N, 8) fp32
    const int*   __restrict__ clusts,      // (C, P)
    const int*   __restrict__ clust_sizes, // (C,)
    const int*   __restrict__ edge_index,  // (2, E)
    float*       __restrict__ out)         // (E, 19) fp32
{
    __shared__ float4 s1[PP];   // src: (x, y, z, sq | +inf if invalid)
    __shared__ float4 s2[PP];   // dst: (-2x, -2y, -2z, sq | +inf if invalid)
    __shared__ float  red_v[4];
    __shared__ int    red_i[4];

    const int e = blockIdx.x;
    const int t = threadIdx.x;

    const int src = edge_index[e];
    const int dst = edge_index[EE + e];
    const int n1  = clust_sizes[src];
    const int n2  = clust_sizes[dst];

    // ---- stage coords (+ squared norms, inf-masked) into LDS ----
    {
        const int which = t >> 7;       // 0 -> s1/src, 1 -> s2/dst
        const int p = t & (PP - 1);
        const int c = which ? dst : src;
        const int n = which ? n2 : n1;
        const int pt = clusts[c * PP + p];
        float4 v = *reinterpret_cast<const float4*>(data + (size_t)pt * 8);
        const float x = v.y, y = v.z, z = v.w;   // cols 1..3
        // numpy order: ((x*x + y*y) + z*z), rn ops, no FMA
        const float sq = __fadd_rn(__fadd_rn(__fmul_rn(x, x), __fmul_rn(y, y)),
                                   __fmul_rn(z, z));
        const float w = (p < n) ? sq : INFINITY;
        float4 o;
        if (which) {
            // pre-scale by -2: rn(-2u) == -2*rn(u) (power-of-2 scale is exact),
            // so the dot-product below reproduces -(2*inner) bit-exactly.
            o.x = -2.0f * x; o.y = -2.0f * y; o.z = -2.0f * z; o.w = w;
            s2[p] = o;
        } else {
            o.x = x; o.y = y; o.z = z; o.w = w;
            s1[p] = o;
        }
    }
    __syncthreads();

    // ---- register-tiled all-pairs argmin: thread owns 4p x 16q ----
    // p = pg + 32*i (contiguous b128 LDS reads across the wave)
    // q = qs*16 + j (wave-broadcast LDS reads)
    const int pg    = t & 31;
    const int qs    = t >> 5;
    const int qbase = qs * 16;

    float4 b[16];
    #pragma unroll
    for (int j = 0; j < 16; ++j) b[j] = s2[qbase + j];
    float4 a[4];
    #pragma unroll
    for (int i = 0; i < 4; ++i) a[i] = s1[pg + 32 * i];

    float bv  = INFINITY;
    int   bij = 0;                 // i*16 + j of current best (inline consts)

    #pragma unroll
    for (int i = 0; i < 4; ++i) {
        const float4 A = a[i];
        #pragma unroll
        for (int j = 0; j < 16; ++j) {
            const float4 B = b[j];
            // m2i == -(2*inner) bit-exactly (see staging comment)
            const float m2i = __fadd_rn(
                __fadd_rn(__fmul_rn(B.x, A.x), __fmul_rn(B.y, A.y)),
                __fmul_rn(B.z, A.z));
            const float sq12 = __fadd_rn(A.w, B.w);
            const float d2   = __fadd_rn(sq12, m2i);
            // nv = min(bv, max(d2, 0)) in one op; eval order is ascending
            // flat idx, so strict < keeps the first-occurrence argmin.
            const float nv = __builtin_amdgcn_fmed3f(d2, 0.0f, bv);
            if (nv < bv) bij = i * 16 + j;
            bv = nv;
        }
    }

    // reconstruct global flat index (p*128 + q) for tie-breaking
    float best_v = bv;
    int   best_i = (pg + ((bij >> 4) << 5)) * PP + (qbase + (bij & 15));

    // ---- wave (64-lane) lexicographic min-reduce on (val, idx) ----
    #pragma unroll
    for (int off = 32; off > 0; off >>= 1) {
        const float ov = __shfl_down(best_v, off);
        const int   oi = __shfl_down(best_i, off);
        if (ov < best_v || (ov == best_v && oi < best_i)) {
            best_v = ov; best_i = oi;
        }
    }
    const int wave = t >> 6;
    if ((t & 63) == 0) { red_v[wave] = best_v; red_i[wave] = best_i; }
    __syncthreads();

    // ---- thread 0: final reduce across 4 waves + epilogue ----
    if (t == 0) {
        float fv = red_v[0]; int fi = red_i[0];
        #pragma unroll
        for (int w = 1; w < 4; ++w) {
            const float ov = red_v[w]; const int oi = red_i[w];
            if (ov < fv || (ov == fv && oi < fi)) { fv = ov; fi = oi; }
        }
        const int i1 = fi >> 7;
        const int i2 = fi & (PP - 1);
        const float4 A  = s1[i1];
        const float4 Bq = s2[i2];
        // undo the -2 pre-scale (exact)
        const float bx = __fmul_rn(Bq.x, -0.5f);
        const float by = __fmul_rn(Bq.y, -0.5f);
        const float bz = __fmul_rn(Bq.z, -0.5f);

        const float d0 = __fsub_rn(A.x, bx);
        const float d1 = __fsub_rn(A.y, by);
        const float d2 = __fsub_rn(A.z, bz);
        const float ss = __fadd_rn(__fadd_rn(__fmul_rn(d0, d0), __fmul_rn(d1, d1)),
                                   __fmul_rn(d2, d2));
        const float lend = __fsqrt_rn(ss);

        float u0 = d0, u1 = d1, u2 = d2;
        if (lend > 0.0f) {
            u0 = __fdiv_rn(d0, lend);
            u1 = __fdiv_rn(d1, lend);
            u2 = __fdiv_rn(d2, lend);
        }

        float* o = out + (size_t)e * 19;
        o[0] = A.x; o[1] = A.y; o[2] = A.z;
        o[3] = bx;  o[4] = by;  o[5] = bz;
        o[6] = u0;  o[7] = u1;  o[8] = u2;
        o[9] = lend;
        o[10] = __fmul_rn(u0, u0); o[11] = __fmul_rn(u0, u1); o[12] = __fmul_rn(u0, u2);
        o[13] = __fmul_rn(u1, u0); o[14] = __fmul_rn(u1, u1); o[15] = __fmul_rn(u1, u2);
        o[16] = __fmul_rn(u2, u0); o[17] = __fmul_rn(u2, u1); o[18] = __fmul_rn(u2, u2);
    }
}

extern "C" void kernel_launch(void* const* d_in, const int* in_sizes, int n_in,
                              void* d_out, int out_size, void* d_ws, size_t ws_size,
                              hipStream_t stream) {
    const float* data        = (const float*)d_in[0];
    const int*   clusts      = (const int*)d_in[1];
    const int*   clust_sizes = (const int*)d_in[2];
    const int*   edge_index  = (const int*)d_in[3];
    float*       out         = (float*)d_out;

    clust_geo_edge_kernel<<<EE, 256, 0, stream>>>(data, clusts, clust_sizes,
                                                  edge_index, out);
}

// Round 3
// 18.418 us; speedup vs baseline: 1.1234x; 1.1234x over previous
//
#include <hip/hip_runtime.h>
#include <math.h>

// Problem constants (match reference file).
#define CC 2048   // clusters
#define PP 128    // max points per cluster
#define EE 2048   // edges

__global__ __launch_bounds__(256) void clust_geo_edge_kernel(
    const float* __restrict__ data,        // (N, 8) fp32
    const int*   __restrict__ clusts,      // (C, P)
    const int*   __restrict__ clust_sizes, // (C,)
    const int*   __restrict__ edge_index,  // (2, E)
    float*       __restrict__ out)         // (E, 19) fp32
{
    __shared__ float4 s1[PP];   // src: (x, y, z, sq | +inf if invalid)
    __shared__ float4 s2[PP];   // dst: (-2x, -2y, -2z, sq | +inf if invalid)
    __shared__ float  red_v[4];
    __shared__ int    red_i[4];

    const int e = blockIdx.x;
    const int t = threadIdx.x;

    const int src = edge_index[e];
    const int dst = edge_index[EE + e];
    const int n1  = clust_sizes[src];
    const int n2  = clust_sizes[dst];

    // ---- stage coords (+ squared norms, inf-masked) into LDS ----
    {
        const int which = t >> 7;       // 0 -> s1/src, 1 -> s2/dst
        const int p = t & (PP - 1);
        const int c = which ? dst : src;
        const int n = which ? n2 : n1;
        const int pt = clusts[c * PP + p];
        float4 v = *reinterpret_cast<const float4*>(data + (size_t)pt * 8);
        const float x = v.y, y = v.z, z = v.w;   // cols 1..3
        // numpy order: ((x*x + y*y) + z*z), rn ops, no FMA
        const float sq = __fadd_rn(__fadd_rn(__fmul_rn(x, x), __fmul_rn(y, y)),
                                   __fmul_rn(z, z));
        const float w = (p < n) ? sq : INFINITY;
        float4 o;
        if (which) {
            // pre-scale by -2: exact (power-of-2), so dot below == -(2*inner)
            // bit-exactly vs the reference's mul-then-scale.
            o.x = -2.0f * x; o.y = -2.0f * y; o.z = -2.0f * z; o.w = w;
            s2[p] = o;
        } else {
            o.x = x; o.y = y; o.z = z; o.w = w;
            s1[p] = o;
        }
    }
    __syncthreads();

    // ---- register-tiled all-pairs argmin, low-pressure layout ----
    // thread owns p = pgid + 8*mi (mi=0..15, A reloaded 4 per group)
    //            q = qid + 32*j  (j=0..3, B live throughout: 4 float4)
    // Eval order: mi outer asc, j inner asc == flat (p*128+q) ascending,
    // so strict < preserves argmin first-occurrence tie-break.
    const int qid  = t & 31;
    const int pgid = t >> 5;    // 0..7

    const float4 b0 = s2[qid];
    const float4 b1 = s2[qid + 32];
    const float4 b2 = s2[qid + 64];
    const float4 b3 = s2[qid + 96];

    float bv = INFINITY;
    int   br = 0;               // rank = mi*4 + j (ascending == flat ascending)

    auto evalp = [&](const float4& A, const float4& B, const int r) {
        // -(2*inner), bit-exact via the -2 pre-scale in s2
        const float m2i = __fadd_rn(
            __fadd_rn(__fmul_rn(B.x, A.x), __fmul_rn(B.y, A.y)),
            __fmul_rn(B.z, A.z));
        const float d2 = __fadd_rn(__fadd_rn(A.w, B.w), m2i);
        // nv = min(bv, max(d2, 0)) in one op
        const float nv = __builtin_amdgcn_fmed3f(d2, 0.0f, bv);
        if (nv < bv) br = r;
        bv = nv;
    };

    #pragma unroll
    for (int g = 0; g < 4; ++g) {
        const float4 a0 = s1[pgid + 8 * (4 * g + 0)];
        const float4 a1 = s1[pgid + 8 * (4 * g + 1)];
        const float4 a2 = s1[pgid + 8 * (4 * g + 2)];
        const float4 a3 = s1[pgid + 8 * (4 * g + 3)];
        evalp(a0, b0, (16 * g) + 0);  evalp(a0, b1, (16 * g) + 1);
        evalp(a0, b2, (16 * g) + 2);  evalp(a0, b3, (16 * g) + 3);
        evalp(a1, b0, (16 * g) + 4);  evalp(a1, b1, (16 * g) + 5);
        evalp(a1, b2, (16 * g) + 6);  evalp(a1, b3, (16 * g) + 7);
        evalp(a2, b0, (16 * g) + 8);  evalp(a2, b1, (16 * g) + 9);
        evalp(a2, b2, (16 * g) + 10); evalp(a2, b3, (16 * g) + 11);
        evalp(a3, b0, (16 * g) + 12); evalp(a3, b1, (16 * g) + 13);
        evalp(a3, b2, (16 * g) + 14); evalp(a3, b3, (16 * g) + 15);
    }

    // reconstruct global flat index (p*128 + q) for cross-thread tie-break
    const int mi = br >> 2;
    const int jj = br & 3;
    float best_v = bv;
    int   best_i = (pgid + 8 * mi) * PP + (qid + 32 * jj);

    // ---- wave (64-lane) lexicographic min-reduce on (val, idx) ----
    #pragma unroll
    for (int off = 32; off > 0; off >>= 1) {
        const float ov = __shfl_down(best_v, off);
        const int   oi = __shfl_down(best_i, off);
        if (ov < best_v || (ov == best_v && oi < best_i)) {
            best_v = ov; best_i = oi;
        }
    }
    const int wave = t >> 6;
    if ((t & 63) == 0) { red_v[wave] = best_v; red_i[wave] = best_i; }
    __syncthreads();

    // ---- thread 0: final reduce across 4 waves + epilogue ----
    if (t == 0) {
        float fv = red_v[0]; int fi = red_i[0];
        #pragma unroll
        for (int w = 1; w < 4; ++w) {
            const float ov = red_v[w]; const int oi = red_i[w];
            if (ov < fv || (ov == fv && oi < fi)) { fv = ov; fi = oi; }
        }
        const int i1 = fi >> 7;
        const int i2 = fi & (PP - 1);
        const float4 A  = s1[i1];
        const float4 Bq = s2[i2];
        // undo the -2 pre-scale (exact)
        const float bx = __fmul_rn(Bq.x, -0.5f);
        const float by = __fmul_rn(Bq.y, -0.5f);
        const float bz = __fmul_rn(Bq.z, -0.5f);

        const float d0 = __fsub_rn(A.x, bx);
        const float d1 = __fsub_rn(A.y, by);
        const float d2 = __fsub_rn(A.z, bz);
        const float ss = __fadd_rn(__fadd_rn(__fmul_rn(d0, d0), __fmul_rn(d1, d1)),
                                   __fmul_rn(d2, d2));
        const float lend = __fsqrt_rn(ss);

        float u0 = d0, u1 = d1, u2 = d2;
        if (lend > 0.0f) {
            u0 = __fdiv_rn(d0, lend);
            u1 = __fdiv_rn(d1, lend);
            u2 = __fdiv_rn(d2, lend);
        }

        float* o = out + (size_t)e * 19;
        o[0] = A.x; o[1] = A.y; o[2] = A.z;
        o[3] = bx;  o[4] = by;  o[5] = bz;
        o[6] = u0;  o[7] = u1;  o[8] = u2;
        o[9] = lend;
        o[10] = __fmul_rn(u0, u0); o[11] = __fmul_rn(u0, u1); o[12] = __fmul_rn(u0, u2);
        o[13] = __fmul_rn(u1, u0); o[14] = __fmul_rn(u1, u1); o[15] = __fmul_rn(u1, u2);
        o[16] = __fmul_rn(u2, u0); o[17] = __fmul_rn(u2, u1); o[18] = __fmul_rn(u2, u2);
    }
}

extern "C" void kernel_launch(void* const* d_in, const int* in_sizes, int n_in,
                              void* d_out, int out_size, void* d_ws, size_t ws_size,
                              hipStream_t stream) {
    const float* data        = (const float*)d_in[0];
    const int*   clusts      = (const int*)d_in[1];
    const int*   clust_sizes = (const int*)d_in[2];
    const int*   edge_index  = (const int*)d_in[3];
    float*       out         = (float*)d_out;

    clust_geo_edge_kernel<<<EE, 256, 0, stream>>>(data, clusts, clust_sizes,
                                                  edge_index, out);
}